// Round 3
// baseline (436.591 us; speedup 1.0000x reference)
//
#include <hip/hip_runtime.h>

typedef _Float16 f16x8 __attribute__((ext_vector_type(8)));
typedef _Float16 f16x4 __attribute__((ext_vector_type(4)));
typedef float    f32x4 __attribute__((ext_vector_type(4)));

#define MFMA(a,b,c) __builtin_amdgcn_mfma_f32_16x16x32_f16((a),(b),(c),0,0,0)

// ws layout (bytes): [0)      M   f16 [128][128]   (scale * Wk^T Wq)
//                    [32768)  Wv' f16 [128][128]   (Wo @ Wv)
//                    [65536)  bf  f32: b'[128] (Wo bv + bo), u[128] (scale * Wk^T bq)
//                    [131072) Xg  f16 [2048 groups][128 rows=(p*32+d)][128 c]  (67.1 MB)

// ---------------- prep: fold weights ----------------
__global__ __launch_bounds__(128) void prep_kernel(
    const float* __restrict__ Wk, const float* __restrict__ bq_,
    const float* __restrict__ Wq, const float* __restrict__ Wv,
    const float* __restrict__ bv, const float* __restrict__ Wo,
    const float* __restrict__ bo,
    _Float16* __restrict__ wh, float* __restrict__ bf) {
  __shared__ float ckl[128], rol[128];
  const int r = blockIdx.x;
  const int c = threadIdx.x;
  const float scale = 0.08838834764831844f;  // 1/sqrt(128)
  ckl[c] = Wk[c*128 + r];      // column r of Wk
  rol[c] = Wo[r*128 + c];      // row r of Wo
  __syncthreads();
  float aM = 0.f, aV = 0.f, a2 = 0.f;
  for (int o = 0; o < 128; ++o) {
    aM += ckl[o] * Wq[o*128 + c];
    aV += rol[o] * Wv[o*128 + c];
    a2 += rol[o] * bv[o];
  }
  wh[r*128 + c]         = (_Float16)(aM * scale);
  wh[16384 + r*128 + c] = (_Float16)aV;
  if (c == 0) bf[r] = a2 + bo[r];
  if (r == 0) {                // u vector (one block)
    float au = 0.f;
    for (int o = 0; o < 128; ++o) au += Wk[o*128 + c] * bq_[o];
    bf[128 + c] = au * scale;
  }
}

// ---------------- transpose: x fp32 [b,c,d,h,w] -> Xg f16 [g][p*32+d][c] ----------------
// LDS-free: 4x4 in-register transpose. Reads full 64B segments, writes 128B-dense runs.
__global__ __launch_bounds__(256) void transpose_kernel(
    const float* __restrict__ x, _Float16* __restrict__ Xg) {
  const int bid = blockIdx.x;
  const int h = bid & 63, d = (bid >> 6) & 31, b = bid >> 11;
  const int t = threadIdx.x;
  const int cg = t & 15, wq = t >> 4;
  const size_t rbase = (size_t)b*16777216u + (size_t)d*4096 + h*64 + wq*4;
  const int gbase = b*1024 + h*16;
  _Float16* dst0 = Xg + (size_t)(gbase + wq)*16384 + d*128;
#pragma unroll
  for (int i = 0; i < 2; ++i) {
    f32x4 v[4];
#pragma unroll
    for (int cc = 0; cc < 4; ++cc)
      v[cc] = *(const f32x4*)(x + rbase + (size_t)(cg*4 + cc + 64*i)*131072u);
#pragma unroll
    for (int r = 0; r < 4; ++r) {
      f16x4 o;
      o[0] = (_Float16)v[0][r]; o[1] = (_Float16)v[1][r];
      o[2] = (_Float16)v[2][r]; o[3] = (_Float16)v[3][r];
      *(f16x4*)(dst0 + r*4096 + cg*4 + 64*i) = o;   // row (r*32+d), c-chunk
    }
  }
}

__device__ __forceinline__ f16x4 cvt4z(f32x4 v) {
  f16x4 r;
  r[0] = (_Float16)v[0]; r[1] = (_Float16)v[1];
  r[2] = (_Float16)v[2]; r[3] = (_Float16)v[3];
  return r;
}

// ---------------- fused attention ----------------
// grid = 2048 blocks x 1024 thr, one pixel-group each; LDS 80384 B -> 2 blocks/CU.
__global__ __launch_bounds__(1024, 8) void attn_kernel(
    const _Float16* __restrict__ Xg, const _Float16* __restrict__ wh,
    const float* __restrict__ bfp, float* __restrict__ out) {
  __shared__ __align__(16) char lds[80384];
  _Float16* Xt = (_Float16*)(lds);            // [128][136] X^T  (row p*32+d, col c)
  _Float16* Yt = (_Float16*)(lds + 34816);    // [128][136] Y^T = (MX)^T ; later U^T
  _Float16* SA = (_Float16*)(lds + 69632);    // [128][40]  S^T then A^T (in-place); u staged first
  float*    al = (float*)(lds + 79872);       // [128] alpha

  const int tid  = threadIdx.x;
  const int lane = tid & 63;
  const int wv   = tid >> 6;
  const int quad = lane >> 4;
  const int l15  = lane & 15;
  const int mi   = wv & 7;
  const int ni   = wv >> 3;

  const int bid = blockIdx.x;
  const int g = (bid & ~31) | ((bid & 7) << 2) | ((bid >> 3) & 3);
  const int b   = g >> 10;
  const int rem = g & 1023;
  const int h   = rem >> 4;
  const int wg  = rem & 15;
  const size_t pbase = (size_t)b * 16777216u + (size_t)(h*64 + wg*4);

  // weight A-fragments in registers (m=l15 row, k=quad*8+j)
  f16x8 wm[4], wp[4];
  {
    const int wrow = (mi*16 + l15) * 128;
#pragma unroll
    for (int kk = 0; kk < 4; ++kk) {
      const int off = wrow + kk*32 + quad*8;
      wm[kk] = *(const f16x8*)(wh + off);
      wp[kk] = *(const f16x8*)(wh + 16384 + off);
    }
  }
  const f32x4 bp4 = *(const f32x4*)(bfp + mi*16 + quad*4);
  const f32x4 zz = {0.f, 0.f, 0.f, 0.f};

  // ---- 1. stage u -> SA area; Xg chunk -> Xt (padded 136) ----
  if (tid < 128) ((float*)SA)[tid] = bfp[128 + tid];
  {
    const _Float16* src = Xg + (size_t)g * 16384;
#pragma unroll
    for (int i = 0; i < 2; ++i) {
      const int idx = tid + i*1024;
      const int row = idx >> 4, ck = (idx & 15) * 8;
      const f16x8 v = *(const f16x8*)(src + row*128 + ck);
      *(f16x8*)(Xt + row*136 + ck) = v;
    }
  }
  __syncthreads();

  // ---- 2. alpha_n = u . x_n ; Y = M . X -> Yt ----
  {
    const int n = tid >> 3, sub = tid & 7;
    const float* us = (const float*)SA;
    const f16x8 x0 = *(const f16x8*)(Xt + n*136 + sub*16);
    const f16x8 x1 = *(const f16x8*)(Xt + n*136 + sub*16 + 8);
    float a = 0.f;
#pragma unroll
    for (int k = 0; k < 8; ++k) a += (float)x0[k] * us[sub*16 + k];
#pragma unroll
    for (int k = 0; k < 8; ++k) a += (float)x1[k] * us[sub*16 + 8 + k];
    a += __shfl_xor(a, 1); a += __shfl_xor(a, 2); a += __shfl_xor(a, 4);
    if (sub == 0) al[n] = a;

    f32x4 aY[4] = {zz, zz, zz, zz};
#pragma unroll
    for (int kk = 0; kk < 4; ++kk) {
      const int co = kk*32 + quad*8;
      f16x8 bfv[4];
#pragma unroll
      for (int nt = 0; nt < 4; ++nt)
        bfv[nt] = *(const f16x8*)(Xt + (ni*64 + nt*16 + l15)*136 + co);
#pragma unroll
      for (int nt = 0; nt < 4; ++nt)
        aY[nt] = MFMA(wm[kk], bfv[nt], aY[nt]);
    }
#pragma unroll
    for (int nt = 0; nt < 4; ++nt)
      *(f16x4*)(Yt + (ni*64 + nt*16 + l15)*136 + mi*16 + quad*4) = cvt4z(aY[nt]);
  }
  __syncthreads();

  // ---- 3. S = X^T . Y per pixel -> SA (f16, S^T: row (p,j), col i) ----
  {
    const int p = wv >> 2, ti = (wv >> 1) & 1, tj = wv & 1;
    f32x4 aS = zz;
#pragma unroll
    for (int kk = 0; kk < 4; ++kk) {
      const int co = kk*32 + quad*8;
      const f16x8 ax = *(const f16x8*)(Xt + (p*32 + ti*16 + l15)*136 + co);
      const f16x8 by = *(const f16x8*)(Yt + (p*32 + tj*16 + l15)*136 + co);
      aS = MFMA(ax, by, aS);
    }
    *(f16x4*)(SA + (p*32 + tj*16 + l15)*40 + ti*16 + quad*4) = cvt4z(aS);
  }
  __syncthreads();

  // ---- 4. softmax over i (+alpha_i), in place, all 1024 threads ----
  {
    const int n = tid >> 3, sub = tid & 7, p = n >> 5;
    f16x4 sv = *(const f16x4*)(SA + n*40 + sub*4);
    float s[4];
#pragma unroll
    for (int k = 0; k < 4; ++k) s[k] = (float)sv[k] + al[p*32 + sub*4 + k];
    float mx = fmaxf(fmaxf(s[0], s[1]), fmaxf(s[2], s[3]));
    mx = fmaxf(mx, __shfl_xor(mx, 1));
    mx = fmaxf(mx, __shfl_xor(mx, 2));
    mx = fmaxf(mx, __shfl_xor(mx, 4));
    float e[4], den = 0.f;
#pragma unroll
    for (int k = 0; k < 4; ++k) { e[k] = __expf(s[k] - mx); den += e[k]; }
    den += __shfl_xor(den, 1); den += __shfl_xor(den, 2); den += __shfl_xor(den, 4);
    const float rr = 1.0f / den;
    f16x4 av;
#pragma unroll
    for (int k = 0; k < 4; ++k) av[k] = (_Float16)(e[k] * rr);
    *(f16x4*)(SA + n*40 + sub*4) = av;
  }
  __syncthreads();

  // ---- 5. U = X . A per pixel; U^T -> Yt (overwrite) ----
  {
    const int p = wv & 3, mg = wv >> 2;
    f16x8 bA[2];
#pragma unroll
    for (int tj = 0; tj < 2; ++tj)
      bA[tj] = *(const f16x8*)(SA + (p*32 + tj*16 + l15)*40 + quad*8);
#pragma unroll
    for (int t2 = 0; t2 < 2; ++t2) {
      const int ms = mg*2 + t2;
      const int cbase = (p*32 + quad*8)*136 + ms*16 + l15;
      const f16x8 ax = { Xt[cbase], Xt[cbase+136], Xt[cbase+272], Xt[cbase+408],
                         Xt[cbase+544], Xt[cbase+680], Xt[cbase+816], Xt[cbase+952] };
#pragma unroll
      for (int tj = 0; tj < 2; ++tj) {
        f32x4 aU = MFMA(ax, bA[tj], zz);
        *(f16x4*)(Yt + (p*32 + tj*16 + l15)*136 + ms*16 + quad*4) = cvt4z(aU);
      }
    }
  }
  __syncthreads();

  // ---- 6. out = Wv'.U + b' + x ; C-init = bias+residual; direct f32x2 stores ----
  {
    f32x4 aO[4];
#pragma unroll
    for (int nt = 0; nt < 4; ++nt) {
      const int base = (ni*64 + nt*16 + l15)*136 + mi*16 + quad*4;
#pragma unroll
      for (int r = 0; r < 4; ++r)
        aO[nt][r] = bp4[r] + (float)Xt[base + r];
    }
#pragma unroll
    for (int kk = 0; kk < 4; ++kk) {
      const int co = kk*32 + quad*8;
      f16x8 bfv[4];
#pragma unroll
      for (int nt = 0; nt < 4; ++nt)
        bfv[nt] = *(const f16x8*)(Yt + (ni*64 + nt*16 + l15)*136 + co);
#pragma unroll
      for (int nt = 0; nt < 4; ++nt)
        aO[nt] = MFMA(wp[kk], bfv[nt], aO[nt]);
    }
#pragma unroll
    for (int ntp = 0; ntp < 2; ++ntp) {
      const int n = ni*64 + ntp*16 + l15;
      const int j = n & 31, p0 = n >> 5;
      const size_t rowb = pbase + (size_t)j*4096 + p0;
#pragma unroll
      for (int r = 0; r < 4; ++r) {
        const int o = mi*16 + quad*4 + r;
        float2 v2 = make_float2(aO[ntp][r], aO[ntp+2][r]);
        *(float2*)(out + rowb + (size_t)o*131072u) = v2;
      }
    }
  }
}

extern "C" void kernel_launch(void* const* d_in, const int* in_sizes, int n_in,
                              void* d_out, int out_size, void* d_ws, size_t ws_size,
                              hipStream_t stream) {
  const float* x  = (const float*)d_in[0];
  const float* Wk = (const float*)d_in[1];
  const float* Wq = (const float*)d_in[3];
  const float* bq = (const float*)d_in[4];
  const float* Wv = (const float*)d_in[5];
  const float* bv = (const float*)d_in[6];
  const float* Wo = (const float*)d_in[7];
  const float* bo = (const float*)d_in[8];
  float* out = (float*)d_out;
  _Float16* wh = (_Float16*)d_ws;
  float* bf = (float*)((char*)d_ws + 65536);
  _Float16* Xg = (_Float16*)((char*)d_ws + 131072);  // 67.1 MB

  prep_kernel<<<dim3(128), dim3(128), 0, stream>>>(Wk, bq, Wq, Wv, bv, Wo, bo, wh, bf);
  transpose_kernel<<<dim3(4096), dim3(256), 0, stream>>>(x, Xg);
  attn_kernel<<<dim3(2048), dim3(1024), 0, stream>>>(Xg, wh, bf, out);
}